// Round 3
// baseline (549.828 us; speedup 1.0000x reference)
//
#include <hip/hip_runtime.h>
#include <math.h>

#define B_ 4
#define S_ 4096
#define D_ 512
#define M_ (B_ * S_)
#define LN_EPS 1e-5f
#define SCALE 0.044194173824159216f   // 1/sqrt(512)
#define LOG2_10000 13.287712379549449f

typedef __attribute__((ext_vector_type(8))) short short8v;   // 8 bf16 (4 VGPR)
typedef __attribute__((ext_vector_type(4))) float f32x4;
typedef __attribute__((ext_vector_type(4))) unsigned short ushort4v;
typedef unsigned short u16;

__device__ __forceinline__ u16 f2bf(float f) {
    union { float f; unsigned u; } v; v.f = f;
    unsigned r = v.u + 0x7fffu + ((v.u >> 16) & 1u);   // RNE
    return (u16)(r >> 16);
}

// ---------------------------------------------------------------------------
// fp32 -> bf16 convert for the four 512x512 weight matrices (one launch).
// ---------------------------------------------------------------------------
__global__ __launch_bounds__(256) void convert_w4(const float* __restrict__ w0,
                                                  const float* __restrict__ w1,
                                                  const float* __restrict__ w2,
                                                  const float* __restrict__ w3,
                                                  u16* __restrict__ o) {
    int mat = blockIdx.x >> 8;
    int i = (blockIdx.x & 255) * 256 + threadIdx.x;      // float4 index in matrix
    const float* w = (mat == 0) ? w0 : (mat == 1) ? w1 : (mat == 2) ? w2 : w3;
    float4 v = ((const float4*)w)[i];
    ushort4v r;
    r.x = f2bf(v.x); r.y = f2bf(v.y); r.z = f2bf(v.z); r.w = f2bf(v.w);
    ((ushort4v*)(o + (size_t)mat * D_ * D_))[i] = r;
}

// ---------------------------------------------------------------------------
// x1 = x + PE (fp32), x1b = bf16(x1)
// pe[s,2i] = sin(s / 10000^((2i+1)/256)), pe[s,2i+1] = cos(same)
// ---------------------------------------------------------------------------
__global__ __launch_bounds__(256) void add_pe_kernel(const float* __restrict__ x,
                                                     float* __restrict__ x1,
                                                     u16* __restrict__ x1b) {
    size_t idx = (size_t)blockIdx.x * 256 + threadIdx.x;   // float4 index
    size_t flat = idx * 4;
    int d = (int)(flat % D_);
    int s = (int)((flat / D_) % S_);

    float4 xv = ((const float4*)x)[idx];
    int i0 = d >> 1;
    float e0 = (float)(2 * i0 + 1) * (1.0f / 256.0f);
    float e1 = (float)(2 * (i0 + 1) + 1) * (1.0f / 256.0f);
    float div0 = exp2f(e0 * LOG2_10000);
    float div1 = exp2f(e1 * LOG2_10000);
    float sf = (float)s;
    float s0, c0, s1, c1;
    sincosf(sf / div0, &s0, &c0);
    sincosf(sf / div1, &s1, &c1);

    float4 r;
    r.x = xv.x + s0; r.y = xv.y + c0; r.z = xv.z + s1; r.w = xv.w + c1;
    ((float4*)x1)[idx] = r;
    ushort4v h;
    h.x = f2bf(r.x); h.y = f2bf(r.y); h.z = f2bf(r.z); h.w = f2bf(r.w);
    ((ushort4v*)x1b)[idx] = h;
}

// ---------------------------------------------------------------------------
// bf16 MFMA GEMM: C[m,n] = A[m,:] . W[n,:] + bias[n]  (+resid)
// Tile 128x64, BK=64, 4 waves (2x2), per-wave 64x32 = 4x2 frags of 16x16x32.
// LDS XOR-swizzle ((row&7)<<4) -> staging writes and frag reads conflict-free
// at 8-lane granularity. MODE 0: bf16 out. MODE 1: bf16 out transposed to
// [b][n][s]. MODE 2: fp32 out + resid.
// ---------------------------------------------------------------------------
template <int MODE>
__global__ __launch_bounds__(256, 2) void gemm_bf16(const u16* __restrict__ A,
                                                    const u16* __restrict__ Wb,
                                                    const float* __restrict__ bias,
                                                    const float* __restrict__ resid,
                                                    void* __restrict__ outp) {
    __shared__ __align__(16) char lds[24576];        // As 16K | Ws 8K
    const int tid = threadIdx.x;
    const int l = tid & 63, wid = tid >> 6;
    const int wr = wid >> 1, wc = wid & 1;
    const int m0 = blockIdx.x * 128, n0 = blockIdx.y * 64;

    f32x4 acc[4][2];
#pragma unroll
    for (int mt = 0; mt < 4; mt++)
#pragma unroll
        for (int nt = 0; nt < 2; nt++) acc[mt][nt] = (f32x4){0.f, 0.f, 0.f, 0.f};

    for (int k0 = 0; k0 < D_; k0 += 64) {
        __syncthreads();
#pragma unroll
        for (int it = 0; it < 4; it++) {             // A tile: 128 rows x 64 k
            int c = it * 256 + tid, row = c >> 3, slot = c & 7;
            short8v v = *(const short8v*)(A + (size_t)(m0 + row) * D_ + k0 + slot * 8);
            *(short8v*)(lds + (row << 7) + ((slot << 4) ^ ((row & 7) << 4))) = v;
        }
#pragma unroll
        for (int it = 0; it < 2; it++) {             // W tile: 64 rows x 64 k
            int c = it * 256 + tid, row = c >> 3, slot = c & 7;
            short8v v = *(const short8v*)(Wb + (size_t)(n0 + row) * D_ + k0 + slot * 8);
            *(short8v*)(lds + 16384 + (row << 7) + ((slot << 4) ^ ((row & 7) << 4))) = v;
        }
        __syncthreads();
#pragma unroll
        for (int kk = 0; kk < 2; kk++) {
            int koff = ((kk << 2) + (l >> 4)) << 4;
            short8v af[4], bf_[2];
#pragma unroll
            for (int mt = 0; mt < 4; mt++) {
                int row = wr * 64 + mt * 16 + (l & 15);
                af[mt] = *(short8v*)(lds + (row << 7) + (koff ^ ((row & 7) << 4)));
            }
#pragma unroll
            for (int nt = 0; nt < 2; nt++) {
                int n = wc * 32 + nt * 16 + (l & 15);
                bf_[nt] = *(short8v*)(lds + 16384 + (n << 7) + (koff ^ ((n & 7) << 4)));
            }
#pragma unroll
            for (int mt = 0; mt < 4; mt++)
#pragma unroll
                for (int nt = 0; nt < 2; nt++)
                    acc[mt][nt] = __builtin_amdgcn_mfma_f32_16x16x32_bf16(
                        af[mt], bf_[nt], acc[mt][nt], 0, 0, 0);
        }
    }

    const int colA = n0 + wc * 32 + (l & 15);        // nt=0 col; nt=1 is +16
    const float bv0 = bias[colA], bv1 = bias[colA + 16];
#pragma unroll
    for (int mt = 0; mt < 4; mt++) {
        int row0 = m0 + wr * 64 + mt * 16 + (l >> 4) * 4;
        if (MODE == 1) {
            ushort4v p0, p1;
#pragma unroll
            for (int i = 0; i < 4; i++) {
                p0[i] = f2bf(acc[mt][0][i] + bv0);
                p1[i] = f2bf(acc[mt][1][i] + bv1);
            }
            int bb = row0 >> 12, s = row0 & (S_ - 1);
            u16* o = (u16*)outp;
            *(ushort4v*)(o + (size_t)bb * D_ * S_ + (size_t)colA * S_ + s) = p0;
            *(ushort4v*)(o + (size_t)bb * D_ * S_ + (size_t)(colA + 16) * S_ + s) = p1;
        } else {
#pragma unroll
            for (int i = 0; i < 4; i++) {
                int row = row0 + i;
                float v0 = acc[mt][0][i] + bv0;
                float v1 = acc[mt][1][i] + bv1;
                size_t off = (size_t)row * D_ + colA;
                if (MODE == 0) {
                    u16* o = (u16*)outp;
                    o[off] = f2bf(v0);
                    o[off + 16] = f2bf(v1);
                } else {
                    float* o = (float*)outp;
                    o[off] = v0 + resid[off];
                    o[off + 16] = v1 + resid[off + 16];
                }
            }
        }
    }
}

// ---------------------------------------------------------------------------
// Flash attention (bf16 MFMA) + residual into x1 (fp32, in place).
// Block: 4 waves, 64 q-rows (16/wave). KV tile = 32 keys.
// LDS: K 32K (row-xor swizzle) | V 32K (unit-permuted: conflict-free at
// 8-lane granularity on both store and PV read) | P 4x2K (128B stride,
// (r&7) unit-xor swizzle).
// ---------------------------------------------------------------------------
__global__ __launch_bounds__(256, 1) void attn_mfma(const u16* __restrict__ q,
                                                    const u16* __restrict__ kmat,
                                                    const u16* __restrict__ vt,
                                                    float* __restrict__ x1) {
    extern __shared__ __align__(16) char lds[];
    const int tid = threadIdx.x;
    const int l = tid & 63, wid = tid >> 6;
    const int bb = blockIdx.y;
    const int q0 = blockIdx.x * 64;

    // Q fragments: 16 k-steps of 16x32; lane l holds row l&15, k (l>>4)*8+e
    short8v qf[16];
    {
        size_t qbase = ((size_t)bb * S_ + q0 + wid * 16 + (l & 15)) * D_;
#pragma unroll
        for (int ks = 0; ks < 16; ks++)
            qf[ks] = *(const short8v*)(q + qbase + ks * 32 + ((l >> 4) << 3));
    }

    f32x4 o[32];
#pragma unroll
    for (int dt = 0; dt < 32; dt++) o[dt] = (f32x4){0.f, 0.f, 0.f, 0.f};
    float mr[4] = {-1e30f, -1e30f, -1e30f, -1e30f};
    float lr[4] = {0.f, 0.f, 0.f, 0.f};

    const u16* kbase = kmat + (size_t)bb * S_ * D_;
    const u16* vbase = vt + (size_t)bb * D_ * S_;
    char* pbase = lds + 65536 + wid * 2048;

    for (int kt = 0; kt < S_; kt += 32) {
        __syncthreads();
        // stage K tile [32 keys][512 d] bf16, row-xor swizzled
#pragma unroll
        for (int it = 0; it < 8; it++) {
            int c = it * 256 + tid, row = c >> 6, slot = c & 63;
            short8v v = *(const short8v*)(kbase + (size_t)(kt + row) * D_ + slot * 8);
            *(short8v*)(lds + (row << 10) + ((slot << 4) ^ ((row & 7) << 4))) = v;
        }
        // stage V tile from vt[b][d][s]: unit(d,kg) = (d&15)*4 + (kg^((d>>1)&3))
#pragma unroll
        for (int it = 0; it < 8; it++) {
            int c = it * 256 + tid, d = c >> 2, kg = c & 3;
            short8v v = *(const short8v*)(vbase + (size_t)d * S_ + kt + kg * 8);
            int unit = ((d & 15) << 2) | (kg ^ ((d >> 1) & 3));
            *(short8v*)(lds + 32768 + ((d >> 4) << 10) + (unit << 4)) = v;
        }
        __syncthreads();

        // QK^T: scores for 16 q-rows x 32 keys
        f32x4 sA = (f32x4){0.f, 0.f, 0.f, 0.f};
        f32x4 sB = (f32x4){0.f, 0.f, 0.f, 0.f};
        {
            int n = l & 15;
            int sw = (n & 7) << 4;
#pragma unroll
            for (int ks = 0; ks < 16; ks++) {
                int koff = ((ks << 2) + (l >> 4)) << 4;
                short8v b0 = *(short8v*)(lds + (n << 10) + (koff ^ sw));
                short8v b1 = *(short8v*)(lds + ((n + 16) << 10) + (koff ^ sw));
                sA = __builtin_amdgcn_mfma_f32_16x16x32_bf16(qf[ks], b0, sA, 0, 0, 0);
                sB = __builtin_amdgcn_mfma_f32_16x16x32_bf16(qf[ks], b1, sB, 0, 0, 0);
            }
        }

        // online softmax (defer-max, THR=8)
        float tm[4];
#pragma unroll
        for (int i = 0; i < 4; i++) {
            sA[i] *= SCALE; sB[i] *= SCALE;
            tm[i] = fmaxf(sA[i], sB[i]);
        }
#pragma unroll
        for (int mask = 8; mask >= 1; mask >>= 1)
#pragma unroll
            for (int i = 0; i < 4; i++) tm[i] = fmaxf(tm[i], __shfl_xor(tm[i], mask));

        bool ok = (tm[0] <= mr[0] + 8.f) && (tm[1] <= mr[1] + 8.f) &&
                  (tm[2] <= mr[2] + 8.f) && (tm[3] <= mr[3] + 8.f);
        if (!__all(ok)) {
            float corr[4];
#pragma unroll
            for (int i = 0; i < 4; i++) {
                float mn = fmaxf(mr[i], tm[i]);
                corr[i] = __expf(mr[i] - mn);
                mr[i] = mn;
                lr[i] *= corr[i];
            }
            f32x4 cv = {corr[0], corr[1], corr[2], corr[3]};
#pragma unroll
            for (int dt = 0; dt < 32; dt++) o[dt] *= cv;
        }

        float pA[4], pB[4], ps[4];
#pragma unroll
        for (int i = 0; i < 4; i++) {
            pA[i] = __expf(sA[i] - mr[i]);
            pB[i] = __expf(sB[i] - mr[i]);
            ps[i] = pA[i] + pB[i];
        }
#pragma unroll
        for (int mask = 8; mask >= 1; mask >>= 1)
#pragma unroll
            for (int i = 0; i < 4; i++) ps[i] += __shfl_xor(ps[i], mask);
#pragma unroll
        for (int i = 0; i < 4; i++) lr[i] += ps[i];

        // P -> LDS bf16 [16 q][32 k] per wave, 128B row stride, unit swizzle
#pragma unroll
        for (int i = 0; i < 4; i++) {
            int r = (l >> 4) * 4 + i;
            int inner = ((l & 15) << 1) & 15;
            int uA = (l & 15) >> 3;              // 0..1
            int uB = 2 + ((l & 15) >> 3);        // 2..3
            *(u16*)(pbase + r * 128 + ((uA ^ (r & 7)) << 4) + inner) = f2bf(pA[i]);
            *(u16*)(pbase + r * 128 + ((uB ^ (r & 7)) << 4) + inner) = f2bf(pB[i]);
        }
        // PV: A-frag P (row l&15, k-unit l>>4), B-frag V units
        {
            short8v pa = *(short8v*)(pbase + ((l & 15) << 7) +
                                     (((l >> 4) ^ ((l & 15) & 7)) << 4));
            int unit = ((l & 15) << 2) | ((l >> 4) ^ ((l >> 1) & 3));
#pragma unroll
            for (int dt = 0; dt < 32; dt++) {
                short8v vb_ = *(short8v*)(lds + 32768 + (dt << 10) + (unit << 4));
                o[dt] = __builtin_amdgcn_mfma_f32_16x16x32_bf16(pa, vb_, o[dt], 0, 0, 0);
            }
        }
    }

    // epilogue: x1 += O / l
#pragma unroll
    for (int i = 0; i < 4; i++) {
        float inv = 1.0f / lr[i];
        size_t rbase = ((size_t)bb * S_ + q0 + wid * 16 + (l >> 4) * 4 + i) * D_;
#pragma unroll
        for (int dt = 0; dt < 32; dt++) {
            size_t a = rbase + dt * 16 + (l & 15);
            x1[a] += o[dt][i] * inv;
        }
    }
}

// ---------------------------------------------------------------------------
// LayerNorm in place (fp32) + bf16 copy for the FF GEMM input
// ---------------------------------------------------------------------------
__global__ __launch_bounds__(256) void lnorm_kernel(float* __restrict__ x,
                                                    const float* __restrict__ g,
                                                    const float* __restrict__ bta,
                                                    u16* __restrict__ xb) {
    int row = blockIdx.x * 4 + (threadIdx.x >> 6);
    int lane = threadIdx.x & 63;
    float* xp = &x[(size_t)row * D_ + lane * 8];
    float4 a = *(const float4*)xp;
    float4 c = *(const float4*)(xp + 4);
    float vals[8] = {a.x, a.y, a.z, a.w, c.x, c.y, c.z, c.w};

    float sum = 0.f;
#pragma unroll
    for (int e = 0; e < 8; e++) sum += vals[e];
#pragma unroll
    for (int mask = 32; mask >= 1; mask >>= 1) sum += __shfl_xor(sum, mask);
    float mu = sum * (1.0f / D_);

    float vs = 0.f;
#pragma unroll
    for (int e = 0; e < 8; e++) { float t = vals[e] - mu; vs += t * t; }
#pragma unroll
    for (int mask = 32; mask >= 1; mask >>= 1) vs += __shfl_xor(vs, mask);
    float rstd = rsqrtf(vs * (1.0f / D_) + LN_EPS);

    const float* gp = &g[lane * 8];
    const float* bp = &bta[lane * 8];
#pragma unroll
    for (int e = 0; e < 8; e++) vals[e] = (vals[e] - mu) * rstd * gp[e] + bp[e];

    float4 ra = {vals[0], vals[1], vals[2], vals[3]};
    float4 rc = {vals[4], vals[5], vals[6], vals[7]};
    *(float4*)xp = ra;
    *(float4*)(xp + 4) = rc;

    ushort4v h0, h1;
#pragma unroll
    for (int e = 0; e < 4; e++) { h0[e] = f2bf(vals[e]); h1[e] = f2bf(vals[e + 4]); }
    u16* xbp = xb + (size_t)row * D_ + lane * 8;
    *(ushort4v*)xbp = h0;
    *(ushort4v*)(xbp + 4) = h1;
}

// ---------------------------------------------------------------------------
extern "C" void kernel_launch(void* const* d_in, const int* in_sizes, int n_in,
                              void* d_out, int out_size, void* d_ws, size_t ws_size,
                              hipStream_t stream) {
    const float* x    = (const float*)d_in[0];
    const float* Wq   = (const float*)d_in[1];
    const float* bq   = (const float*)d_in[2];
    const float* Wk   = (const float*)d_in[3];
    const float* bk   = (const float*)d_in[4];
    const float* Wv   = (const float*)d_in[5];
    const float* bv   = (const float*)d_in[6];
    const float* ln_g = (const float*)d_in[7];
    const float* ln_b = (const float*)d_in[8];
    const float* Wf   = (const float*)d_in[9];
    const float* bf   = (const float*)d_in[10];
    float* out = (float*)d_out;

    char* w = (char*)d_ws;
    float* x1 = (float*)w;                        // [0,32M) fp32 x+pe / resid
    u16* x1b = (u16*)(w + 33554432);              // [32M,48M) bf16 x+pe
    u16* qbf = (u16*)(w + 50331648);              // [48M,64M) q; reused as x2b
    u16* kbf = (u16*)(w + 67108864);              // [64M,80M) k
    u16* vtb = (u16*)(w + 83886080);              // [80M,96M) v^T [b][d][s]
    u16* wcvt = (u16*)(w + 100663296);            // [96M,+2M) 4 bf16 weights
    u16* x2b = qbf;                               // LN output bf16 (q is dead)

    convert_w4<<<1024, 256, 0, stream>>>(Wq, Wk, Wv, Wf, wcvt);

    add_pe_kernel<<<8192, 256, 0, stream>>>(x, x1, x1b);

    dim3 ggrid(M_ / 128, D_ / 64);
    gemm_bf16<0><<<ggrid, 256, 0, stream>>>(x1b, wcvt,              bq, nullptr, qbf);
    gemm_bf16<0><<<ggrid, 256, 0, stream>>>(x1b, wcvt + 262144,     bk, nullptr, kbf);
    gemm_bf16<1><<<ggrid, 256, 0, stream>>>(x1b, wcvt + 524288,     bv, nullptr, vtb);

    attn_mfma<<<dim3(S_ / 64, B_), 256, 73728, stream>>>(qbf, kbf, vtb, x1);

    lnorm_kernel<<<M_ / 4, 256, 0, stream>>>(x1, ln_g, ln_b, x2b);

    gemm_bf16<2><<<ggrid, 256, 0, stream>>>(x2b, wcvt + 786432, bf, x1, out);
}